// Round 11
// baseline (264.242 us; speedup 1.0000x reference)
//
#include <hip/hip_runtime.h>
#include <math.h>

#define N_NODES 20000
#define N_EDGES 320000
#define EMB 128
#define HID 512          // 4*EMB
#define NCHUNK ((N_NODES + 1023) / 1024)   // 20

// fused_edge geometry (round-7 champion, FROZEN)
#define RPW 2
#define WPB 4
#define RPB (RPW * WPB)                    // 8
#define FE_BLOCKS ((N_NODES + RPB - 1) / RPB)  // 2500

// MFMA gemm geometry: block tile 256(M) x 64(N), 4 waves of 64x64
#define GEMM_MT ((N_NODES + 255) / 256)    // 79
#define GEMM_NT 16                         // 1024 / 64
#define GEMM_MFMA_BLOCKS (GEMM_MT * GEMM_NT)   // 1264 = 8*158
#define HIST_BLOCKS ((N_EDGES + 255) / 256)    // 1250
#define GH_BLOCKS (GEMM_MFMA_BLOCKS + HIST_BLOCKS)  // 2514
#define N_HTILES (N_NODES / 16)            // 1250 (exact)

// prep block ranges: h-split pack, W-split pack, deg zero
#define PREP_H_BLOCKS 2500                 // 20000*128/4 float4 / 256thr
#define PREP_W_BLOCKS 64                   // 16384 threads (8 k per thread)
#define PREP_Z_BLOCKS ((N_NODES + 255) / 256)   // 79
#define PREP_BLOCKS (PREP_H_BLOCKS + PREP_W_BLOCKS + PREP_Z_BLOCKS)

typedef __attribute__((ext_vector_type(8))) short bf16x8;  // 8 bf16 = 4 VGPR
typedef __attribute__((ext_vector_type(4))) float f32x4;

#define MFMA16(a, b, c) __builtin_amdgcn_mfma_f32_16x16x32_bf16((a), (b), (c), 0, 0, 0)

// async global->LDS: per-lane GLOBAL source, wave-uniform LDS base + lane*16.
__device__ __forceinline__ void stage16(const unsigned short* g, unsigned short* l) {
    __builtin_amdgcn_global_load_lds(
        (const __attribute__((address_space(1))) void*)g,
        (__attribute__((address_space(3))) void*)l, 16, 0, 0);
}

// ---------------------------------------------------------------------------
// bf16x3 split helpers (round-to-nearest-even bf16; exact residual chain)
// ---------------------------------------------------------------------------
__device__ __forceinline__ unsigned short bf16rn(float x) {
    unsigned u = __builtin_bit_cast(unsigned, x);
    u += 0x7FFFu + ((u >> 16) & 1u);
    return (unsigned short)(u >> 16);
}
__device__ __forceinline__ float bf2f(unsigned short b) {
    unsigned u = ((unsigned)b) << 16;
    return __builtin_bit_cast(float, u);
}
__device__ __forceinline__ void split3(float x, unsigned short& s1,
                                       unsigned short& s2, unsigned short& s3) {
    s1 = bf16rn(x);
    float r = x - bf2f(s1);
    s2 = bf16rn(r);
    float r2 = r - bf2f(s2);
    s3 = bf16rn(r2);
}

// ---------------------------------------------------------------------------
// prep_pack (exact round-7 version): packed-fragment bf16x3 split writes for
// h and W, plus deg zeroing. Fragment layout: elem (t, ks, lane, j) at
// (t*4+ks)*512 + lane*8 + j where source row r = t*16 + (lane&15),
// k = ks*32 + (lane>>4)*8 + j.
// [r8 lesson: pre-split stays HERE — fp32 on-the-fly split in gemm spilled
//  the accumulator. r10 lesson: hist does NOT belong here (+5us vs on-gemm).]
// ---------------------------------------------------------------------------
__global__ __launch_bounds__(256) void prep_pack(
    const float* __restrict__ h, const float* __restrict__ W1,
    unsigned short* __restrict__ hp1, unsigned short* __restrict__ hp2,
    unsigned short* __restrict__ hp3,
    unsigned short* __restrict__ wp1, unsigned short* __restrict__ wp2,
    unsigned short* __restrict__ wp3,
    int* __restrict__ deg, int* __restrict__ offs)
{
    const int bid = blockIdx.x, tid = threadIdx.x;

    if (bid < PREP_H_BLOCKS) {
        const int i4 = bid * 256 + tid;              // float4 index, exact fit
        const float4 v = ((const float4*)h)[i4];
        const int r  = i4 >> 5;                      // 32 float4 per row
        const int k0 = (i4 & 31) << 2;
        const int t = r >> 4, rowi = r & 15;
        const int ks = k0 >> 5;
        const int ln = (((k0 >> 3) & 3) << 4) + rowi;
        const int j0 = k0 & 7;                       // 0 or 4 -> 8B aligned
        const size_t off = (size_t)((t * 4 + ks) * 512) + ln * 8 + j0;
        unsigned short a1[4], a2[4], a3[4];
        split3(v.x, a1[0], a2[0], a3[0]);
        split3(v.y, a1[1], a2[1], a3[1]);
        split3(v.z, a1[2], a2[2], a3[2]);
        split3(v.w, a1[3], a2[3], a3[3]);
#define PACK4(dst, a) { \
            uint2 pk; \
            pk.x = (unsigned)a[0] | ((unsigned)a[1] << 16); \
            pk.y = (unsigned)a[2] | ((unsigned)a[3] << 16); \
            *(uint2*)((dst) + off) = pk; }
        PACK4(hp1, a1); PACK4(hp2, a2); PACK4(hp3, a3);
#undef PACK4
        return;
    }

    if (bid < PREP_H_BLOCKS + PREP_W_BLOCKS) {
        // W path: thread handles 8 consecutive k for one output col n.
        const int t = (bid - PREP_H_BLOCKS) * 256 + tid;   // 16384 exact
        const int n = t & 1023, kg = t >> 10;              // kg in [0,16)
        const int k0 = kg << 3;
        const int wrow0 = ((n >> 9) << 7) + k0;
        const int wcol  = n & 511;
        unsigned short s1[8], s2[8], s3[8];
#pragma unroll
        for (int j = 0; j < 8; ++j) {
            const float x = W1[(size_t)(wrow0 + j) * HID + wcol];
            split3(x, s1[j], s2[j], s3[j]);
        }
        const int tn = n >> 4, rown = n & 15;
        const int ks = k0 >> 5;
        const int ln = (((k0 >> 3) & 3) << 4) + rown;
        const size_t off = (size_t)((tn * 4 + ks) * 512) + ln * 8;
#define PACK8(dst, a) { \
            uint4 pk; \
            pk.x = (unsigned)a[0] | ((unsigned)a[1] << 16); \
            pk.y = (unsigned)a[2] | ((unsigned)a[3] << 16); \
            pk.z = (unsigned)a[4] | ((unsigned)a[5] << 16); \
            pk.w = (unsigned)a[6] | ((unsigned)a[7] << 16); \
            *(uint4*)((dst) + off) = pk; }
        PACK8(wp1, s1); PACK8(wp2, s2); PACK8(wp3, s3);
#undef PACK8
        return;
    }

    // deg zero path (hist runs in the NEXT kernel -> stream-ordered, no race)
    const int i = (bid - PREP_H_BLOCKS - PREP_W_BLOCKS) * 256 + tid;
    if (i < N_NODES) deg[i] = 0;
    if (i == 0) offs[N_NODES] = N_EDGES;
}

// ---------------------------------------------------------------------------
// gemm_mfma + histogram — EXACT round-7 champion (total 253.7us config).
//  * hist rides gemm's idle wave-slots (r10 proved moving it out costs +5us).
//  * XCD swizzle: 16 nt-blocks sharing an A-tile run on ONE XCD's L2.
//  * MFMA order: product-outer / jn / i-inner (dep distance 16); per-acc
//    product order (11,12,21,22,13,31) -> bitwise-identical output.
//  * B (48 KB) staged once via global_load_lds; A bf16 reg-double-buffered.
//  * __launch_bounds__(256,2): (256,3) spills the 64-VGPR accumulator (r8).
// ---------------------------------------------------------------------------
__global__ __launch_bounds__(256, 2) void gemm_mfma(
    const unsigned short* __restrict__ hp1, const unsigned short* __restrict__ hp2,
    const unsigned short* __restrict__ hp3,
    const unsigned short* __restrict__ wp1, const unsigned short* __restrict__ wp2,
    const unsigned short* __restrict__ wp3,
    const float* __restrict__ b1, float* __restrict__ P, float* __restrict__ Q,
    const int* __restrict__ row, int* __restrict__ deg)
{
    const int bid = blockIdx.x;
    const int tid = threadIdx.x;

    if (bid >= GEMM_MFMA_BLOCKS) {
        // ---- histogram path ----
        const int e = (bid - GEMM_MFMA_BLOCKS) * 256 + tid;
        if (e < N_EDGES) atomicAdd(&deg[row[e]], 1);
        return;
    }

    __shared__ unsigned short bs[4][4][3][512];   // [jn][ks][split][1KB] = 48KB

    // XCD-contiguous logical block id (1264 = 8*158, bijective)
    const int lb = (bid & 7) * (GEMM_MFMA_BLOCKS / 8) + (bid >> 3);
    const int mt = lb >> 4, nt = lb & 15;
    const int lane = tid & 63, w = tid >> 6;
    const int l15 = lane & 15, l4 = lane >> 4;

    // ---- stage B: wave w stages its jn=w column sub-tile (12 chunks) ----
    {
        const int tn = nt * 4 + w;            // packed w-tile index (< 64)
#pragma unroll
        for (int ks = 0; ks < 4; ++ks) {
            const size_t so = (size_t)((tn * 4 + ks) * 512) + lane * 8;
            stage16(wp1 + so, &bs[w][ks][0][0]);
            stage16(wp2 + so, &bs[w][ks][1][0]);
            stage16(wp3 + so, &bs[w][ks][2][0]);
        }
    }

    // ---- A tile indices + ks=0 preload ----
    int tA[4];
#pragma unroll
    for (int i = 0; i < 4; ++i) {
        int t = mt * 16 + w * 4 + i;
        tA[i] = (t < N_HTILES) ? t : N_HTILES - 1;   // clamp; stores guarded
    }
    size_t aoff[4];
#pragma unroll
    for (int i = 0; i < 4; ++i)
        aoff[i] = (size_t)(tA[i] * 4) * 512 + lane * 8;

    bf16x8 A1[4], A2[4], A3[4];
#pragma unroll
    for (int i = 0; i < 4; ++i) {
        A1[i] = *(const bf16x8*)(hp1 + aoff[i]);
        A2[i] = *(const bf16x8*)(hp2 + aoff[i]);
        A3[i] = *(const bf16x8*)(hp3 + aoff[i]);
    }

    f32x4 acc[4][4];
#pragma unroll
    for (int i = 0; i < 4; ++i)
#pragma unroll
        for (int j = 0; j < 4; ++j) acc[i][j] = (f32x4){0.f, 0.f, 0.f, 0.f};

    __syncthreads();   // drains vmcnt: B staged + A ks=0 resident

#pragma unroll
    for (int ks = 0; ks < 4; ++ks) {
        bf16x8 N1[4], N2[4], N3[4];
        if (ks < 3) {
            const size_t ko = (size_t)(ks + 1) * 512;
#pragma unroll
            for (int i = 0; i < 4; ++i) {
                N1[i] = *(const bf16x8*)(hp1 + aoff[i] + ko);
                N2[i] = *(const bf16x8*)(hp2 + aoff[i] + ko);
                N3[i] = *(const bf16x8*)(hp3 + aoff[i] + ko);
            }
        }
        // 6 split-products, p-outer / jn / i-inner
#define PROD(AA, SP) \
        { _Pragma("unroll") \
          for (int jn = 0; jn < 4; ++jn) { \
              const bf16x8 Bv = *(const bf16x8*)(&bs[jn][ks][SP][0] + lane * 8); \
              _Pragma("unroll") \
              for (int i = 0; i < 4; ++i) \
                  acc[i][jn] = MFMA16(AA[i], Bv, acc[i][jn]); \
          } }
        PROD(A1, 0) PROD(A1, 1) PROD(A2, 0) PROD(A2, 1) PROD(A1, 2) PROD(A3, 0)
#undef PROD
        if (ks < 3) {
#pragma unroll
            for (int i = 0; i < 4; ++i) {
                A1[i] = N1[i]; A2[i] = N2[i]; A3[i] = N3[i];
            }
        }
    }

    // store: D lane l, reg r -> row (l>>4)*4+r, col l&15 (m89-verified)
    const int rb0 = mt * 256 + w * 64;
#pragma unroll
    for (int jn = 0; jn < 4; ++jn) {
        const int n = nt * 64 + jn * 16 + l15;
        const bool isP = n < 512;
        float* __restrict__ dst = isP ? P : Q;
        const int col = n & 511;
        const float bias = isP ? b1[col] : 0.0f;
#pragma unroll
        for (int i = 0; i < 4; ++i) {
            const int rr0 = rb0 + i * 16 + l4 * 4;
#pragma unroll
            for (int r = 0; r < 4; ++r) {
                const int rr = rr0 + r;
                if (rr < N_NODES)
                    dst[(size_t)rr * HID + col] = acc[i][jn][r] + bias;
            }
        }
    }
}

// ---------------------------------------------------------------------------
__device__ __forceinline__ int wave_incl_scan(int v, int lane) {
#pragma unroll
    for (int off = 1; off < 64; off <<= 1) {
        int t = __shfl_up(v, off, 64);
        if (lane >= off) v += t;
    }
    return v;
}

// ---------------------------------------------------------------------------
// scan_all (round-11): scan_part+scan_apply merged into ONE single-block
// kernel (1x1024). [r9 lesson: NO cooperative launch — +33us. Single block
// needs only __syncthreads.] All 20 chunk loads issued up-front (full unroll,
// static indexing per rule-20) so one memory latency covers the whole scan.
// Removes one dispatch + its gap + the part[] round-trip.
// ---------------------------------------------------------------------------
__global__ __launch_bounds__(1024) void scan_all(const int* __restrict__ deg,
                                                 int* __restrict__ cursor,
                                                 int* __restrict__ offs)
{
    __shared__ int wsum[16];
    __shared__ int btot;
    const int tid = threadIdx.x, lane = tid & 63, w = tid >> 6;

    int vv[NCHUNK];
#pragma unroll
    for (int c = 0; c < NCHUNK; ++c) {
        const int i = c * 1024 + tid;
        vv[c] = (i < N_NODES) ? deg[i] : 0;   // 20 independent loads in flight
    }

    int carry = 0;
#pragma unroll
    for (int c = 0; c < NCHUNK; ++c) {
        const int i = c * 1024 + tid;
        const int v = vv[c];
        int incl = wave_incl_scan(v, lane);
        if (lane == 63) wsum[w] = incl;
        __syncthreads();
        if (w == 0) {
            int x = (lane < 16) ? wsum[lane] : 0;
            int xs = wave_incl_scan(x, lane);
            if (lane < 16) wsum[lane] = xs - x;   // exclusive wave offset
            if (lane == 15) btot = xs;            // chunk total
        }
        __syncthreads();
        if (i < N_NODES) {
            const int o = carry + wsum[w] + incl - v;
            cursor[i] = o;
            offs[i] = o;
        }
        carry += btot;
        __syncthreads();   // wsum/btot reused next iteration
    }
}

// ---------------------------------------------------------------------------
__global__ void scatter_edges(const int* __restrict__ row, const int* __restrict__ col,
                              int* __restrict__ cursor,
                              unsigned short* __restrict__ cols16,
                              int* __restrict__ inv) {
    int e = blockIdx.x * 256 + threadIdx.x;
    if (e >= N_EDGES) return;
    int r = row[e];
    int pos = atomicAdd(&cursor[r], 1);
    cols16[pos] = (unsigned short)col[e];
    inv[e] = pos;
}

// ---------------------------------------------------------------------------
// Fused edge phase — FROZEN round-7 champion (97.4us; fill 3.3 TB/s is the
// structural ceiling for the random Q gather: FETCH = 8 XCD x Q across five
// different structures, occupancy-invariant).
// ---------------------------------------------------------------------------
__device__ __forceinline__ float dot8_relu(const float4 qa, const float4 qb,
                                           const float4 p0, const float4 p1,
                                           const float4 w0, const float4 w1) {
    float t = 0.0f;
    t = fmaf(fmaxf(p0.x + qa.x, 0.0f), w0.x, t);
    t = fmaf(fmaxf(p0.y + qa.y, 0.0f), w0.y, t);
    t = fmaf(fmaxf(p0.z + qa.z, 0.0f), w0.z, t);
    t = fmaf(fmaxf(p0.w + qa.w, 0.0f), w0.w, t);
    t = fmaf(fmaxf(p1.x + qb.x, 0.0f), w1.x, t);
    t = fmaf(fmaxf(p1.y + qb.y, 0.0f), w1.y, t);
    t = fmaf(fmaxf(p1.z + qb.z, 0.0f), w1.z, t);
    t = fmaf(fmaxf(p1.w + qb.w, 0.0f), w1.w, t);
    return t;
}

__device__ __forceinline__ float chunk_scores(
    const float* __restrict__ Q, const unsigned short* __restrict__ cols16,
    int es_base, int nch, int lane, int j0,
    const float4 p0, const float4 p1, const float4 w0, const float4 w1,
    float bias2)
{
    int mycol = 0;
    if (lane < nch) mycol = (int)cols16[es_base + lane];
    float mysc = -INFINITY;

#define QL2(k, bb, d0, d1) { \
        int c_ = __shfl(mycol, (bb) + (k), 64); \
        const float* __restrict__ q_ = Q + (size_t)c_ * HID; \
        d0 = *(const float4*)(q_ + j0); \
        d1 = *(const float4*)(q_ + 256 + j0); }

    float4 a00, a01, a10, a11;
    QL2(0, 0, a00, a01); QL2(1, 0, a10, a11);

    for (int b = 0; b < nch; b += 2) {
        float4 n00, n01, n10, n11;
        const bool more = (b + 2) < nch;
        if (more) { QL2(0, b + 2, n00, n01); QL2(1, b + 2, n10, n11); }

        float s0 = dot8_relu(a00, a01, p0, p1, w0, w1);
        float s1 = dot8_relu(a10, a11, p0, p1, w0, w1);

#pragma unroll
        for (int off = 32; off > 0; off >>= 1) {
            s0 += __shfl_xor(s0, off, 64);
            s1 += __shfl_xor(s1, off, 64);
        }

        const int k = lane - b;
        if ((unsigned)k < 2u && lane < nch) mysc = (k ? s1 : s0) + bias2;

        if (more) { a00 = n00; a01 = n01; a10 = n10; a11 = n11; }
    }
#undef QL2
    return mysc;
}

__global__ __launch_bounds__(256) void fused_edge(
    const float* __restrict__ P, const float* __restrict__ Q,
    const float* __restrict__ W2, const float* __restrict__ b2,
    const unsigned short* __restrict__ cols16, const int* __restrict__ offs,
    float2* __restrict__ tmp)
{
    const int tid = threadIdx.x, lane = tid & 63, w = tid >> 6;
    const int r0 = blockIdx.x * RPB + w * RPW;
    const int r1 = (r0 + RPW < N_NODES) ? r0 + RPW : N_NODES;
    const int j0 = lane << 2;

    const float4 w0 = *(const float4*)(W2 + j0);
    const float4 w1 = *(const float4*)(W2 + 256 + j0);
    const float bias2 = b2[0];

    for (int r = r0; r < r1; ++r) {
        const int es = offs[r], ee = offs[r + 1];
        const int d = ee - es;
        if (d == 0) continue;

        const float* __restrict__ prow = P + (size_t)r * HID;
        const float4 p0 = *(const float4*)(prow + j0);
        const float4 p1 = *(const float4*)(prow + 256 + j0);

        if (d <= 64) {
            float mysc = chunk_scores(Q, cols16, es, d, lane, j0,
                                      p0, p1, w0, w1, bias2);

            float m = mysc;
#pragma unroll
            for (int off = 32; off > 0; off >>= 1)
                m = fmaxf(m, __shfl_xor(m, off, 64));

            float ev = (lane < d) ? expf(mysc - m) : 0.0f;
            float ssum = ev;
#pragma unroll
            for (int off = 32; off > 0; off >>= 1)
                ssum += __shfl_xor(ssum, off, 64);

            if (lane < d) {
                float p = ev / ssum;
                float logits = logf(p) - log1pf(-p);   // +inf when p==1 (d==1)
                tmp[es + lane] = make_float2(mysc, logits);
            }
        } else {
            for (int base = 0; base < d; base += 64) {
                const int nch = (d - base < 64) ? d - base : 64;
                float mysc = chunk_scores(Q, cols16, es + base, nch, lane, j0,
                                          p0, p1, w0, w1, bias2);
                if (lane < nch) tmp[es + base + lane].x = mysc;
            }

            float m = -INFINITY;
            for (int j = lane; j < d; j += 64)
                m = fmaxf(m, tmp[es + j].x);
#pragma unroll
            for (int off = 32; off > 0; off >>= 1)
                m = fmaxf(m, __shfl_xor(m, off, 64));

            float ssum = 0.0f;
            for (int j = lane; j < d; j += 64)
                ssum += expf(tmp[es + j].x - m);
#pragma unroll
            for (int off = 32; off > 0; off >>= 1)
                ssum += __shfl_xor(ssum, off, 64);

            for (int j = lane; j < d; j += 64) {
                float s = tmp[es + j].x;
                float p = expf(s - m) / ssum;
                float logits = logf(p) - log1pf(-p);
                tmp[es + j] = make_float2(s, logits);
            }
        }
    }
}

// ---------------------------------------------------------------------------
__global__ __launch_bounds__(256) void unperm(
    const float2* __restrict__ tmp, const int* __restrict__ inv,
    const float* __restrict__ u, const int* __restrict__ edge_mask,
    const int* __restrict__ hierarchy,
    float* __restrict__ scores, float* __restrict__ out_y,
    float* __restrict__ out_mask, float* __restrict__ out_causal,
    float* __restrict__ out_spu)
{
    const int e = blockIdx.x * 256 + threadIdx.x;
    if (e >= N_EDGES) return;
    const float2 t = tmp[inv[e]];
    const float s = t.x;
    const float uu = u[e];
    const float L = logf(uu) - log1pf(-uu);
    const float y = 1.0f / (1.0f + expf(-(t.y + L)));
    const bool hard = y > 0.5f;                    // ST forward value == y_hard
    const int mm = hard ? (hierarchy[0] + 1) : edge_mask[e];
    scores[e]     = s;
    out_y[e]      = hard ? 1.0f : 0.0f;
    out_mask[e]   = (float)mm;
    out_causal[e] = (mm > 0)   ?  s : 0.0f;
    out_spu[e]    = (mm == -1) ? -s : 0.0f;
}

// ---------------------------------------------------------------------------
extern "C" void kernel_launch(void* const* d_in, const int* in_sizes, int n_in,
                              void* d_out, int out_size, void* d_ws, size_t ws_size,
                              hipStream_t stream) {
    const float* h_ptr = (const float*)d_in[0];
    const float* W1    = (const float*)d_in[1];
    const float* b1    = (const float*)d_in[2];
    const float* W2    = (const float*)d_in[3];
    const float* b2    = (const float*)d_in[4];
    const float* u     = (const float*)d_in[5];
    const int*   row   = (const int*)d_in[6];
    const int*   col   = (const int*)d_in[7];
    const int*   emask = (const int*)d_in[8];
    const int*   hier  = (const int*)d_in[9];

    float* out        = (float*)d_out;
    float* scores     = out;                        // [E]
    float* out_y      = out + (size_t)N_EDGES;      // [E]
    float* out_mask   = out + 2 * (size_t)N_EDGES;  // [E]
    float* out_causal = out + 3 * (size_t)N_EDGES;  // [E]
    float* out_spu    = out + 4 * (size_t)N_EDGES;  // [E]

    // workspace (r7 layout): P, Q fp32; packed hp1..3 bf16; packed wp1..3
    // bf16; small int arrays (part[] removed — scan_all carries it in regs).
    // tmp/cols16/inv ALIAS the hp region (hp dead after gemm_mfma; first
    // written by scatter_edges which runs after).
    float*          P      = (float*)d_ws;
    float*          Qm     = P + (size_t)N_NODES * HID;
    unsigned short* hp1    = (unsigned short*)(Qm + (size_t)N_NODES * HID);
    unsigned short* hp2    = hp1 + (size_t)N_NODES * EMB;
    unsigned short* hp3    = hp2 + (size_t)N_NODES * EMB;
    unsigned short* wp1    = hp3 + (size_t)N_NODES * EMB;
    unsigned short* wp2    = wp1 + 1024 * 128;
    unsigned short* wp3    = wp2 + 1024 * 128;
    int*            deg    = (int*)(wp3 + 1024 * 128);
    int*            cursor = deg + N_NODES;
    int*            offs   = cursor + N_NODES;      // [N_NODES+1]
    float2*         tmp    = (float2*)hp1;                      // [E] 2.56MB
    unsigned short* cols16 = (unsigned short*)(tmp + N_EDGES);  // [E] u16
    int*            inv    = (int*)(cols16 + N_EDGES);          // [E]

    hipLaunchKernelGGL(prep_pack, dim3(PREP_BLOCKS), dim3(256), 0, stream,
                       h_ptr, W1, hp1, hp2, hp3, wp1, wp2, wp3, deg, offs);

    hipLaunchKernelGGL(gemm_mfma, dim3(GH_BLOCKS), dim3(256), 0, stream,
                       hp1, hp2, hp3, wp1, wp2, wp3, b1, P, Qm, row, deg);

    hipLaunchKernelGGL(scan_all, dim3(1), dim3(1024), 0, stream,
                       deg, cursor, offs);

    hipLaunchKernelGGL(scatter_edges, dim3((N_EDGES + 255) / 256), dim3(256), 0, stream,
                       row, col, cursor, cols16, inv);

    hipLaunchKernelGGL(fused_edge, dim3(FE_BLOCKS), dim3(256), 0, stream,
                       P, Qm, W2, b2, cols16, offs, tmp);

    hipLaunchKernelGGL(unperm, dim3((N_EDGES + 255) / 256), dim3(256), 0, stream,
                       tmp, inv, u, emask, hier,
                       scores, out_y, out_mask, out_causal, out_spu);
}

// Round 12
// 243.817 us; speedup vs baseline: 1.0838x; 1.0838x over previous
//
#include <hip/hip_runtime.h>
#include <math.h>

#define N_NODES 20000
#define N_EDGES 320000
#define EMB 128
#define HID 512          // 4*EMB
#define NCHUNK ((N_NODES + 1023) / 1024)   // 20

// fused_edge geometry (round-7 champion, FROZEN)
#define RPW 2
#define WPB 4
#define RPB (RPW * WPB)                    // 8
#define FE_BLOCKS ((N_NODES + RPB - 1) / RPB)  // 2500

// MFMA gemm geometry: block tile 256(M) x 64(N), 4 waves of 64x64
#define GEMM_MT ((N_NODES + 255) / 256)    // 79
#define GEMM_NT 16                         // 1024 / 64
#define GEMM_MFMA_BLOCKS (GEMM_MT * GEMM_NT)   // 1264 = 8*158
#define HIST_BLOCKS ((N_EDGES + 255) / 256)    // 1250
#define GH_BLOCKS (GEMM_MFMA_BLOCKS + HIST_BLOCKS)  // 2514
#define N_HTILES (N_NODES / 16)            // 1250 (exact)

// prep block ranges: h-split pack, W-split pack, deg zero
#define PREP_H_BLOCKS 2500                 // 20000*128/4 float4 / 256thr
#define PREP_W_BLOCKS 64                   // 16384 threads (8 k per thread)
#define PREP_Z_BLOCKS ((N_NODES + 255) / 256)   // 79
#define PREP_BLOCKS (PREP_H_BLOCKS + PREP_W_BLOCKS + PREP_Z_BLOCKS)

typedef __attribute__((ext_vector_type(8))) short bf16x8;  // 8 bf16 = 4 VGPR
typedef __attribute__((ext_vector_type(4))) float f32x4;

#define MFMA16(a, b, c) __builtin_amdgcn_mfma_f32_16x16x32_bf16((a), (b), (c), 0, 0, 0)

// async global->LDS: per-lane GLOBAL source, wave-uniform LDS base + lane*16.
__device__ __forceinline__ void stage16(const unsigned short* g, unsigned short* l) {
    __builtin_amdgcn_global_load_lds(
        (const __attribute__((address_space(1))) void*)g,
        (__attribute__((address_space(3))) void*)l, 16, 0, 0);
}

// ---------------------------------------------------------------------------
// bf16x3 split helpers (round-to-nearest-even bf16; exact residual chain)
// ---------------------------------------------------------------------------
__device__ __forceinline__ unsigned short bf16rn(float x) {
    unsigned u = __builtin_bit_cast(unsigned, x);
    u += 0x7FFFu + ((u >> 16) & 1u);
    return (unsigned short)(u >> 16);
}
__device__ __forceinline__ float bf2f(unsigned short b) {
    unsigned u = ((unsigned)b) << 16;
    return __builtin_bit_cast(float, u);
}
__device__ __forceinline__ void split3(float x, unsigned short& s1,
                                       unsigned short& s2, unsigned short& s3) {
    s1 = bf16rn(x);
    float r = x - bf2f(s1);
    s2 = bf16rn(r);
    float r2 = r - bf2f(s2);
    s3 = bf16rn(r2);
}

// ---------------------------------------------------------------------------
// prep_pack (exact round-7 version): packed-fragment bf16x3 split writes for
// h and W, plus deg zeroing. Fragment layout: elem (t, ks, lane, j) at
// (t*4+ks)*512 + lane*8 + j where source row r = t*16 + (lane&15),
// k = ks*32 + (lane>>4)*8 + j.
// [r8: pre-split stays HERE (on-the-fly split spilled acc). r10: hist does
//  NOT belong here (+6.6us). r11: single-block scan merge was negative.]
// ---------------------------------------------------------------------------
__global__ __launch_bounds__(256) void prep_pack(
    const float* __restrict__ h, const float* __restrict__ W1,
    unsigned short* __restrict__ hp1, unsigned short* __restrict__ hp2,
    unsigned short* __restrict__ hp3,
    unsigned short* __restrict__ wp1, unsigned short* __restrict__ wp2,
    unsigned short* __restrict__ wp3,
    int* __restrict__ deg, int* __restrict__ offs)
{
    const int bid = blockIdx.x, tid = threadIdx.x;

    if (bid < PREP_H_BLOCKS) {
        const int i4 = bid * 256 + tid;              // float4 index, exact fit
        const float4 v = ((const float4*)h)[i4];
        const int r  = i4 >> 5;                      // 32 float4 per row
        const int k0 = (i4 & 31) << 2;
        const int t = r >> 4, rowi = r & 15;
        const int ks = k0 >> 5;
        const int ln = (((k0 >> 3) & 3) << 4) + rowi;
        const int j0 = k0 & 7;                       // 0 or 4 -> 8B aligned
        const size_t off = (size_t)((t * 4 + ks) * 512) + ln * 8 + j0;
        unsigned short a1[4], a2[4], a3[4];
        split3(v.x, a1[0], a2[0], a3[0]);
        split3(v.y, a1[1], a2[1], a3[1]);
        split3(v.z, a1[2], a2[2], a3[2]);
        split3(v.w, a1[3], a2[3], a3[3]);
#define PACK4(dst, a) { \
            uint2 pk; \
            pk.x = (unsigned)a[0] | ((unsigned)a[1] << 16); \
            pk.y = (unsigned)a[2] | ((unsigned)a[3] << 16); \
            *(uint2*)((dst) + off) = pk; }
        PACK4(hp1, a1); PACK4(hp2, a2); PACK4(hp3, a3);
#undef PACK4
        return;
    }

    if (bid < PREP_H_BLOCKS + PREP_W_BLOCKS) {
        // W path: thread handles 8 consecutive k for one output col n.
        const int t = (bid - PREP_H_BLOCKS) * 256 + tid;   // 16384 exact
        const int n = t & 1023, kg = t >> 10;              // kg in [0,16)
        const int k0 = kg << 3;
        const int wrow0 = ((n >> 9) << 7) + k0;
        const int wcol  = n & 511;
        unsigned short s1[8], s2[8], s3[8];
#pragma unroll
        for (int j = 0; j < 8; ++j) {
            const float x = W1[(size_t)(wrow0 + j) * HID + wcol];
            split3(x, s1[j], s2[j], s3[j]);
        }
        const int tn = n >> 4, rown = n & 15;
        const int ks = k0 >> 5;
        const int ln = (((k0 >> 3) & 3) << 4) + rown;
        const size_t off = (size_t)((tn * 4 + ks) * 512) + ln * 8;
#define PACK8(dst, a) { \
            uint4 pk; \
            pk.x = (unsigned)a[0] | ((unsigned)a[1] << 16); \
            pk.y = (unsigned)a[2] | ((unsigned)a[3] << 16); \
            pk.z = (unsigned)a[4] | ((unsigned)a[5] << 16); \
            pk.w = (unsigned)a[6] | ((unsigned)a[7] << 16); \
            *(uint4*)((dst) + off) = pk; }
        PACK8(wp1, s1); PACK8(wp2, s2); PACK8(wp3, s3);
#undef PACK8
        return;
    }

    // deg zero path (hist runs in the NEXT kernel -> stream-ordered, no race)
    const int i = (bid - PREP_H_BLOCKS - PREP_W_BLOCKS) * 256 + tid;
    if (i < N_NODES) deg[i] = 0;
    if (i == 0) offs[N_NODES] = N_EDGES;
}

// ---------------------------------------------------------------------------
// gemm_mfma + histogram — round-7 champion body; ONLY change this round:
// C-store routed through LDS (reusing the dead bs buffer) so global stores
// are fully-coalesced float4 rows (256B segments, 16 stores/thread) instead
// of 64 scattered dwords (64B segments). Values bit-identical.
//  * hist rides gemm's idle wave-slots (r10 proved moving it out costs +6us).
//  * XCD swizzle; MFMA order p-outer/jn/i-inner; per-acc product order
//    (11,12,21,22,13,31) unchanged -> bitwise-identical output.
//  * __launch_bounds__(256,2): (256,3) spills the accumulator (r8).
// ---------------------------------------------------------------------------
__global__ __launch_bounds__(256, 2) void gemm_mfma(
    const unsigned short* __restrict__ hp1, const unsigned short* __restrict__ hp2,
    const unsigned short* __restrict__ hp3,
    const unsigned short* __restrict__ wp1, const unsigned short* __restrict__ wp2,
    const unsigned short* __restrict__ wp3,
    const float* __restrict__ b1, float* __restrict__ P, float* __restrict__ Q,
    const int* __restrict__ row, int* __restrict__ deg)
{
    const int bid = blockIdx.x;
    const int tid = threadIdx.x;

    if (bid >= GEMM_MFMA_BLOCKS) {
        // ---- histogram path ----
        const int e = (bid - GEMM_MFMA_BLOCKS) * 256 + tid;
        if (e < N_EDGES) atomicAdd(&deg[row[e]], 1);
        return;
    }

    __shared__ unsigned short bs[4][4][3][512];   // [jn][ks][split][1KB] = 48KB

    // XCD-contiguous logical block id (1264 = 8*158, bijective)
    const int lb = (bid & 7) * (GEMM_MFMA_BLOCKS / 8) + (bid >> 3);
    const int mt = lb >> 4, nt = lb & 15;
    const int lane = tid & 63, w = tid >> 6;
    const int l15 = lane & 15, l4 = lane >> 4;

    // ---- stage B: wave w stages its jn=w column sub-tile (12 chunks) ----
    {
        const int tn = nt * 4 + w;            // packed w-tile index (< 64)
#pragma unroll
        for (int ks = 0; ks < 4; ++ks) {
            const size_t so = (size_t)((tn * 4 + ks) * 512) + lane * 8;
            stage16(wp1 + so, &bs[w][ks][0][0]);
            stage16(wp2 + so, &bs[w][ks][1][0]);
            stage16(wp3 + so, &bs[w][ks][2][0]);
        }
    }

    // ---- A tile indices + ks=0 preload ----
    int tA[4];
#pragma unroll
    for (int i = 0; i < 4; ++i) {
        int t = mt * 16 + w * 4 + i;
        tA[i] = (t < N_HTILES) ? t : N_HTILES - 1;   // clamp; stores guarded
    }
    size_t aoff[4];
#pragma unroll
    for (int i = 0; i < 4; ++i)
        aoff[i] = (size_t)(tA[i] * 4) * 512 + lane * 8;

    bf16x8 A1[4], A2[4], A3[4];
#pragma unroll
    for (int i = 0; i < 4; ++i) {
        A1[i] = *(const bf16x8*)(hp1 + aoff[i]);
        A2[i] = *(const bf16x8*)(hp2 + aoff[i]);
        A3[i] = *(const bf16x8*)(hp3 + aoff[i]);
    }

    f32x4 acc[4][4];
#pragma unroll
    for (int i = 0; i < 4; ++i)
#pragma unroll
        for (int j = 0; j < 4; ++j) acc[i][j] = (f32x4){0.f, 0.f, 0.f, 0.f};

    __syncthreads();   // drains vmcnt: B staged + A ks=0 resident

#pragma unroll
    for (int ks = 0; ks < 4; ++ks) {
        bf16x8 N1[4], N2[4], N3[4];
        if (ks < 3) {
            const size_t ko = (size_t)(ks + 1) * 512;
#pragma unroll
            for (int i = 0; i < 4; ++i) {
                N1[i] = *(const bf16x8*)(hp1 + aoff[i] + ko);
                N2[i] = *(const bf16x8*)(hp2 + aoff[i] + ko);
                N3[i] = *(const bf16x8*)(hp3 + aoff[i] + ko);
            }
        }
        // 6 split-products, p-outer / jn / i-inner
#define PROD(AA, SP) \
        { _Pragma("unroll") \
          for (int jn = 0; jn < 4; ++jn) { \
              const bf16x8 Bv = *(const bf16x8*)(&bs[jn][ks][SP][0] + lane * 8); \
              _Pragma("unroll") \
              for (int i = 0; i < 4; ++i) \
                  acc[i][jn] = MFMA16(AA[i], Bv, acc[i][jn]); \
          } }
        PROD(A1, 0) PROD(A1, 1) PROD(A2, 0) PROD(A2, 1) PROD(A1, 2) PROD(A3, 0)
#undef PROD
        if (ks < 3) {
#pragma unroll
            for (int i = 0; i < 4; ++i) {
                A1[i] = N1[i]; A2[i] = N2[i]; A3[i] = N3[i];
            }
        }
    }

    // ---- coalesced C store via per-wave LDS transpose (bit-identical) ----
    // D frag: lane l, reg r -> tile row i*16 + (l>>4)*4 + r, col jn*16+(l&15).
    // Stage half (32 rows x 64 cols) into wave-private LDS (stride 68 floats:
    // rows 16B-aligned, <=2-way bank aliasing = free), read back as float4
    // rows -> 256B-segment global stores, 16 lanes contiguous.
    __syncthreads();   // all waves done reading bs -> safe to reuse as f32
    {
        float* __restrict__ lds_f = (float*)&bs[0][0][0][0] + w * (32 * 68);
        const bool isP = nt < 8;
        float* __restrict__ dstb = isP ? P : Q;
        const int colb = (nt & 7) * 64;
        float bias_l[4];
#pragma unroll
        for (int jn = 0; jn < 4; ++jn)
            bias_l[jn] = isP ? b1[colb + jn * 16 + l15] : 0.0f;
        const int rb0 = mt * 256 + w * 64;

#pragma unroll
        for (int half = 0; half < 2; ++half) {
            // write this half's acc into LDS (wave-private; in-order per wave)
#pragma unroll
            for (int ii = 0; ii < 2; ++ii) {
                const int i = half * 2 + ii;
#pragma unroll
                for (int jn = 0; jn < 4; ++jn) {
#pragma unroll
                    for (int r = 0; r < 4; ++r) {
                        const int lrow = ii * 16 + l4 * 4 + r;   // 0..31
                        lds_f[lrow * 68 + jn * 16 + l15] = acc[i][jn][r] + bias_l[jn];
                    }
                }
            }
            // read back coalesced: 4 rows/iter, lane l -> row l>>4, f4 col l&15
#pragma unroll
            for (int it = 0; it < 8; ++it) {
                const int lrow = it * 4 + l4;
                const float4 vv = *(const float4*)&lds_f[lrow * 68 + l15 * 4];
                const int rr = rb0 + half * 32 + lrow;
                if (rr < N_NODES)
                    *(float4*)&dstb[(size_t)rr * HID + colb + l15 * 4] = vv;
            }
        }
    }
}

// ---------------------------------------------------------------------------
__device__ __forceinline__ int wave_incl_scan(int v, int lane) {
#pragma unroll
    for (int off = 1; off < 64; off <<= 1) {
        int t = __shfl_up(v, off, 64);
        if (lane >= off) v += t;
    }
    return v;
}

// Two plain scan kernels (r7 form). [r9: NO cooperative launch (+33us).
//  r11: single-block merged scan was also negative — keep the 20-block pair.]
__global__ __launch_bounds__(1024) void scan_part(const int* __restrict__ deg,
                                                  int* __restrict__ part,
                                                  int* __restrict__ totals) {
    __shared__ int wsum[16];
    const int tid = threadIdx.x, lane = tid & 63, w = tid >> 6;
    const int i = blockIdx.x * 1024 + tid;
    int v = (i < N_NODES) ? deg[i] : 0;
    int incl = wave_incl_scan(v, lane);
    if (lane == 63) wsum[w] = incl;
    __syncthreads();
    if (w == 0) {
        int x = (lane < 16) ? wsum[lane] : 0;
        int xs = wave_incl_scan(x, lane);
        if (lane < 16) wsum[lane] = xs - x;
        if (lane == 15) totals[blockIdx.x] = xs;
    }
    __syncthreads();
    if (i < N_NODES) part[i] = wsum[w] + incl - v;
}

__global__ __launch_bounds__(1024) void scan_apply(const int* __restrict__ part,
                                                   const int* __restrict__ totals,
                                                   int* __restrict__ cursor,
                                                   int* __restrict__ offs) {
    __shared__ int carry_s;
    const int tid = threadIdx.x;
    if (tid < 64) {
        int v = (tid < NCHUNK) ? totals[tid] : 0;
        int incl = wave_incl_scan(v, tid);
        if (tid == (int)blockIdx.x) carry_s = incl - v;   // exclusive carry
    }
    __syncthreads();
    const int i = blockIdx.x * 1024 + tid;
    if (i < N_NODES) {
        int o = part[i] + carry_s;
        cursor[i] = o;
        offs[i] = o;
    }
}

// ---------------------------------------------------------------------------
__global__ void scatter_edges(const int* __restrict__ row, const int* __restrict__ col,
                              int* __restrict__ cursor,
                              unsigned short* __restrict__ cols16,
                              int* __restrict__ inv) {
    int e = blockIdx.x * 256 + threadIdx.x;
    if (e >= N_EDGES) return;
    int r = row[e];
    int pos = atomicAdd(&cursor[r], 1);
    cols16[pos] = (unsigned short)col[e];
    inv[e] = pos;
}

// ---------------------------------------------------------------------------
// Fused edge phase — FROZEN round-7 champion (97.4us; fill 3.3 TB/s is the
// structural ceiling for the random Q gather: FETCH = 8 XCD x Q across five
// different structures, occupancy-invariant).
// ---------------------------------------------------------------------------
__device__ __forceinline__ float dot8_relu(const float4 qa, const float4 qb,
                                           const float4 p0, const float4 p1,
                                           const float4 w0, const float4 w1) {
    float t = 0.0f;
    t = fmaf(fmaxf(p0.x + qa.x, 0.0f), w0.x, t);
    t = fmaf(fmaxf(p0.y + qa.y, 0.0f), w0.y, t);
    t = fmaf(fmaxf(p0.z + qa.z, 0.0f), w0.z, t);
    t = fmaf(fmaxf(p0.w + qa.w, 0.0f), w0.w, t);
    t = fmaf(fmaxf(p1.x + qb.x, 0.0f), w1.x, t);
    t = fmaf(fmaxf(p1.y + qb.y, 0.0f), w1.y, t);
    t = fmaf(fmaxf(p1.z + qb.z, 0.0f), w1.z, t);
    t = fmaf(fmaxf(p1.w + qb.w, 0.0f), w1.w, t);
    return t;
}

__device__ __forceinline__ float chunk_scores(
    const float* __restrict__ Q, const unsigned short* __restrict__ cols16,
    int es_base, int nch, int lane, int j0,
    const float4 p0, const float4 p1, const float4 w0, const float4 w1,
    float bias2)
{
    int mycol = 0;
    if (lane < nch) mycol = (int)cols16[es_base + lane];
    float mysc = -INFINITY;

#define QL2(k, bb, d0, d1) { \
        int c_ = __shfl(mycol, (bb) + (k), 64); \
        const float* __restrict__ q_ = Q + (size_t)c_ * HID; \
        d0 = *(const float4*)(q_ + j0); \
        d1 = *(const float4*)(q_ + 256 + j0); }

    float4 a00, a01, a10, a11;
    QL2(0, 0, a00, a01); QL2(1, 0, a10, a11);

    for (int b = 0; b < nch; b += 2) {
        float4 n00, n01, n10, n11;
        const bool more = (b + 2) < nch;
        if (more) { QL2(0, b + 2, n00, n01); QL2(1, b + 2, n10, n11); }

        float s0 = dot8_relu(a00, a01, p0, p1, w0, w1);
        float s1 = dot8_relu(a10, a11, p0, p1, w0, w1);

#pragma unroll
        for (int off = 32; off > 0; off >>= 1) {
            s0 += __shfl_xor(s0, off, 64);
            s1 += __shfl_xor(s1, off, 64);
        }

        const int k = lane - b;
        if ((unsigned)k < 2u && lane < nch) mysc = (k ? s1 : s0) + bias2;

        if (more) { a00 = n00; a01 = n01; a10 = n10; a11 = n11; }
    }
#undef QL2
    return mysc;
}

__global__ __launch_bounds__(256) void fused_edge(
    const float* __restrict__ P, const float* __restrict__ Q,
    const float* __restrict__ W2, const float* __restrict__ b2,
    const unsigned short* __restrict__ cols16, const int* __restrict__ offs,
    float2* __restrict__ tmp)
{
    const int tid = threadIdx.x, lane = tid & 63, w = tid >> 6;
    const int r0 = blockIdx.x * RPB + w * RPW;
    const int r1 = (r0 + RPW < N_NODES) ? r0 + RPW : N_NODES;
    const int j0 = lane << 2;

    const float4 w0 = *(const float4*)(W2 + j0);
    const float4 w1 = *(const float4*)(W2 + 256 + j0);
    const float bias2 = b2[0];

    for (int r = r0; r < r1; ++r) {
        const int es = offs[r], ee = offs[r + 1];
        const int d = ee - es;
        if (d == 0) continue;

        const float* __restrict__ prow = P + (size_t)r * HID;
        const float4 p0 = *(const float4*)(prow + j0);
        const float4 p1 = *(const float4*)(prow + 256 + j0);

        if (d <= 64) {
            float mysc = chunk_scores(Q, cols16, es, d, lane, j0,
                                      p0, p1, w0, w1, bias2);

            float m = mysc;
#pragma unroll
            for (int off = 32; off > 0; off >>= 1)
                m = fmaxf(m, __shfl_xor(m, off, 64));

            float ev = (lane < d) ? expf(mysc - m) : 0.0f;
            float ssum = ev;
#pragma unroll
            for (int off = 32; off > 0; off >>= 1)
                ssum += __shfl_xor(ssum, off, 64);

            if (lane < d) {
                float p = ev / ssum;
                float logits = logf(p) - log1pf(-p);   // +inf when p==1 (d==1)
                tmp[es + lane] = make_float2(mysc, logits);
            }
        } else {
            for (int base = 0; base < d; base += 64) {
                const int nch = (d - base < 64) ? d - base : 64;
                float mysc = chunk_scores(Q, cols16, es + base, nch, lane, j0,
                                          p0, p1, w0, w1, bias2);
                if (lane < nch) tmp[es + base + lane].x = mysc;
            }

            float m = -INFINITY;
            for (int j = lane; j < d; j += 64)
                m = fmaxf(m, tmp[es + j].x);
#pragma unroll
            for (int off = 32; off > 0; off >>= 1)
                m = fmaxf(m, __shfl_xor(m, off, 64));

            float ssum = 0.0f;
            for (int j = lane; j < d; j += 64)
                ssum += expf(tmp[es + j].x - m);
#pragma unroll
            for (int off = 32; off > 0; off >>= 1)
                ssum += __shfl_xor(ssum, off, 64);

            for (int j = lane; j < d; j += 64) {
                float s = tmp[es + j].x;
                float p = expf(s - m) / ssum;
                float logits = logf(p) - log1pf(-p);
                tmp[es + j] = make_float2(s, logits);
            }
        }
    }
}

// ---------------------------------------------------------------------------
__global__ __launch_bounds__(256) void unperm(
    const float2* __restrict__ tmp, const int* __restrict__ inv,
    const float* __restrict__ u, const int* __restrict__ edge_mask,
    const int* __restrict__ hierarchy,
    float* __restrict__ scores, float* __restrict__ out_y,
    float* __restrict__ out_mask, float* __restrict__ out_causal,
    float* __restrict__ out_spu)
{
    const int e = blockIdx.x * 256 + threadIdx.x;
    if (e >= N_EDGES) return;
    const float2 t = tmp[inv[e]];
    const float s = t.x;
    const float uu = u[e];
    const float L = logf(uu) - log1pf(-uu);
    const float y = 1.0f / (1.0f + expf(-(t.y + L)));
    const bool hard = y > 0.5f;                    // ST forward value == y_hard
    const int mm = hard ? (hierarchy[0] + 1) : edge_mask[e];
    scores[e]     = s;
    out_y[e]      = hard ? 1.0f : 0.0f;
    out_mask[e]   = (float)mm;
    out_causal[e] = (mm > 0)   ?  s : 0.0f;
    out_spu[e]    = (mm == -1) ? -s : 0.0f;
}

// ---------------------------------------------------------------------------
extern "C" void kernel_launch(void* const* d_in, const int* in_sizes, int n_in,
                              void* d_out, int out_size, void* d_ws, size_t ws_size,
                              hipStream_t stream) {
    const float* h_ptr = (const float*)d_in[0];
    const float* W1    = (const float*)d_in[1];
    const float* b1    = (const float*)d_in[2];
    const float* W2    = (const float*)d_in[3];
    const float* b2    = (const float*)d_in[4];
    const float* u     = (const float*)d_in[5];
    const int*   row   = (const int*)d_in[6];
    const int*   col   = (const int*)d_in[7];
    const int*   emask = (const int*)d_in[8];
    const int*   hier  = (const int*)d_in[9];

    float* out        = (float*)d_out;
    float* scores     = out;                        // [E]
    float* out_y      = out + (size_t)N_EDGES;      // [E]
    float* out_mask   = out + 2 * (size_t)N_EDGES;  // [E]
    float* out_causal = out + 3 * (size_t)N_EDGES;  // [E]
    float* out_spu    = out + 4 * (size_t)N_EDGES;  // [E]

    // workspace (r7 layout): P, Q fp32; packed hp1..3 bf16; packed wp1..3
    // bf16; small int arrays. tmp/cols16/inv ALIAS the hp region (hp dead
    // after gemm_mfma; first written by scatter_edges which runs after).
    float*          P      = (float*)d_ws;
    float*          Qm     = P + (size_t)N_NODES * HID;
    unsigned short* hp1    = (unsigned short*)(Qm + (size_t)N_NODES * HID);
    unsigned short* hp2    = hp1 + (size_t)N_NODES * EMB;
    unsigned short* hp3    = hp2 + (size_t)N_NODES * EMB;
    unsigned short* wp1    = hp3 + (size_t)N_NODES * EMB;
    unsigned short* wp2    = wp1 + 1024 * 128;
    unsigned short* wp3    = wp2 + 1024 * 128;
    int*            deg    = (int*)(wp3 + 1024 * 128);
    int*            cursor = deg + N_NODES;
    int*            offs   = cursor + N_NODES;      // [N_NODES+1]
    int*            part   = offs + N_NODES + 1;
    int*            totals = part + N_NODES;        // [NCHUNK]
    float2*         tmp    = (float2*)hp1;                      // [E] 2.56MB
    unsigned short* cols16 = (unsigned short*)(tmp + N_EDGES);  // [E] u16
    int*            inv    = (int*)(cols16 + N_EDGES);          // [E]

    hipLaunchKernelGGL(prep_pack, dim3(PREP_BLOCKS), dim3(256), 0, stream,
                       h_ptr, W1, hp1, hp2, hp3, wp1, wp2, wp3, deg, offs);

    hipLaunchKernelGGL(gemm_mfma, dim3(GH_BLOCKS), dim3(256), 0, stream,
                       hp1, hp2, hp3, wp1, wp2, wp3, b1, P, Qm, row, deg);

    hipLaunchKernelGGL(scan_part, dim3(NCHUNK), dim3(1024), 0, stream, deg, part, totals);
    hipLaunchKernelGGL(scan_apply, dim3(NCHUNK), dim3(1024), 0, stream,
                       part, totals, cursor, offs);
    hipLaunchKernelGGL(scatter_edges, dim3((N_EDGES + 255) / 256), dim3(256), 0, stream,
                       row, col, cursor, cols16, inv);

    hipLaunchKernelGGL(fused_edge, dim3(FE_BLOCKS), dim3(256), 0, stream,
                       P, Qm, W2, b2, cols16, offs, tmp);

    hipLaunchKernelGGL(unperm, dim3((N_EDGES + 255) / 256), dim3(256), 0, stream,
                       tmp, inv, u, emask, hier,
                       scores, out_y, out_mask, out_causal, out_spu);
}